// Round 3
// baseline (828.250 us; speedup 1.0000x reference)
//
#include <hip/hip_runtime.h>

// deltaLayer: out[b,c,i,j] = |l[b,c,j] - r[b,c,i]|
// BS=2, CHAN=128, H=1, W=900 -> out is (2,128,900,900) fp32 = 829.4 MB.
// Pure write-BW bound.
//
// R1: occupancy 16->32 waves/CU + unroll-5: only +15% => not latency-bound.
// R2: NT store -> plain store: -16us => NT exonerated. Kernel ~280us
//     (~2.95 TB/s) vs 137us the poison fill proves on the same buffer.
// R3: eliminate ALL per-store baggage. Thread t permanently owns output
//     columns 4t..4t+3; sweep rows:
//       - lv = l[4t..4t+3] loaded ONCE into VGPRs (LDS eliminated)
//       - rv = r[i] block-uniform -> compiler scalarizes to s_load
//       - no magic divide; store address = constant-stride increment
//     Inner loop = s_load + 4 v_sub + 4 v_and + global_store_dwordx4,
//     structurally identical to the 6.29 TB/s fill kernel.

#define BS    2
#define CHAN  128
#define W     900
#define W4    225                 // float4 per output row
#define TILE4 (W * W4)            // 202500 float4 per (b,c) tile
#define SPLIT 18                  // blocks per (b,c) tile
#define ROWS  50                  // W / SPLIT rows per block

typedef float v4f __attribute__((ext_vector_type(4)));

__global__ __launch_bounds__(256, 8)
void deltaLayer_57294863728910_kernel(const float* __restrict__ l,
                                      const float* __restrict__ r,
                                      float* __restrict__ out) {
    const int bc = blockIdx.y;        // (b*CHAN + c), 0..255
    const int i0 = blockIdx.x * ROWS; // first row of this block's band
    const int t  = threadIdx.x;
    if (t >= W4) return;              // threads 225..255 idle

    const v4f lv = ((const v4f*)(l + bc * W))[t];   // loop-invariant
    const float* rp = r + bc * W + i0;              // block-uniform reads

    v4f* ob = (v4f*)out + (size_t)bc * TILE4 + (size_t)i0 * W4 + t;

    #pragma unroll 5
    for (int i = 0; i < ROWS; ++i) {
        float rv = rp[i];             // uniform -> s_load_dword
        v4f o;
        o.x = fabsf(lv.x - rv);
        o.y = fabsf(lv.y - rv);
        o.z = fabsf(lv.z - rv);
        o.w = fabsf(lv.w - rv);
        ob[(size_t)i * W4] = o;       // global_store_dwordx4, stride 3600B
    }
}

extern "C" void kernel_launch(void* const* d_in, const int* in_sizes, int n_in,
                              void* d_out, int out_size, void* d_ws, size_t ws_size,
                              hipStream_t stream) {
    const float* l = (const float*)d_in[0];
    const float* r = (const float*)d_in[1];
    float* out = (float*)d_out;

    dim3 grid(SPLIT, BS * CHAN);    // 4608 blocks
    dim3 block(256);
    deltaLayer_57294863728910_kernel<<<grid, block, 0, stream>>>(l, r, out);
}